// Round 1
// baseline (27206.198 us; speedup 1.0000x reference)
//
#include <hip/hip_runtime.h>
#include <math.h>

#define S 16384
#define T 1024
#define B 64
#define NSTEP (S - 1)   // 16383 transitions
#define CH 64           // chunk length for fwd/backtrack
#define NC 256          // number of chunks

#define K2E 1.44269504088896340736f  // log2(e)
#define LN2 0.69314718055994530942f
#define LN64 4.15888308335967186f

// ---------------- workspace layout (bytes) ----------------
static constexpr size_t SZ_SB   = (size_t)S * B * 4;        // 4 MB
static constexpr size_t OFF_BS  = 0;                        // best_scores f32 [S][B]
static constexpr size_t OFF_BT  = OFF_BS + SZ_SB;           // best_tags  i32 [S][B]
static constexpr size_t OFF_VIT = OFF_BT + SZ_SB;           // vit values f32 [S][B]
static constexpr size_t OFF_BP  = OFF_VIT + SZ_SB;          // backptrs   i32 [S][B] (t>=1)
static constexpr size_t OFF_GT  = OFF_BP + SZ_SB;           // chunk G^T  f32 [NC][B][B]
static constexpr size_t SZ_GT   = (size_t)NC * B * B * 4;   // 4 MB
static constexpr size_t OFF_MAP = OFF_GT + SZ_GT;           // chunk maps i32 [NC][B]
static constexpr size_t OFF_BND = OFF_MAP + (size_t)NC * B * 4; // boundary states i32 [NC+1]
static constexpr size_t OFF_SCAL= OFF_BND + 4096;           // scal[0] = base+crf
static constexpr size_t OFF_W   = OFF_SCAL + 4096;          // pre-gathered W f32 [NSTEP][B(j)][B(i)]
static constexpr size_t SZ_W    = (size_t)NSTEP * B * B * 4; // ~256 MB

// ---------------- K1: per-row top-64 (bitwise matches jax.lax.top_k ordering) ----------------
__global__ __launch_bounds__(64) void k_topk(const float* __restrict__ scores,
                                             float* __restrict__ bs, int* __restrict__ bt) {
  int row = blockIdx.x;
  int lane = threadIdx.x;
  const float* rp = scores + (size_t)row * T;
  float v[16];
#pragma unroll
  for (int k = 0; k < 16; ++k) v[k] = rp[k * 64 + lane];
  for (int b = 0; b < B; ++b) {
    // lane-local argmax (ascending k, strict > keeps smallest element index)
    float lv = v[0]; int lk = 0;
#pragma unroll
    for (int k = 1; k < 16; ++k) {
      if (v[k] > lv) { lv = v[k]; lk = k; }
    }
    float bv = lv; int be = lk * 64 + lane;
    // wave argmax, ties -> smaller element index (matches stable top_k)
#pragma unroll
    for (int off = 32; off >= 1; off >>= 1) {
      float ov = __shfl_xor(bv, off);
      int   oe = __shfl_xor(be, off);
      if (ov > bv || (ov == bv && oe < be)) { bv = ov; be = oe; }
    }
    if (lane == 0) {
      bs[(size_t)row * B + b] = bv;
      bt[(size_t)row * B + b] = be;
    }
    // clear the extracted element (owner lane only)
    int bk = be >> 6, bl = be & 63;
#pragma unroll
    for (int k = 0; k < 16; ++k) {
      if (k == bk && lane == bl) v[k] = -3.0e38f;
    }
  }
}

// ---------------- K2: pre-gather per-step weight tiles: Wp[t-1][j][i] = w[pt_i][ct_j] ----------------
__global__ __launch_bounds__(256) void k_pregather(const float* __restrict__ wt,
                                                   const int* __restrict__ bt,
                                                   float* __restrict__ Wp) {
  size_t n = (size_t)blockIdx.x * 256 + threadIdx.x;  // one float4 (4 i's) per thread
  int i4  = (int)(n & 15);
  int j   = (int)((n >> 4) & 63);
  int tm1 = (int)(n >> 10);
  if (tm1 >= NSTEP) return;
  int ct = bt[(size_t)(tm1 + 1) * B + j];
  const int* pt = bt + (size_t)tm1 * B + i4 * 4;
  float4 o;
  o.x = wt[(size_t)pt[0] * T + ct];
  o.y = wt[(size_t)pt[1] * T + ct];
  o.z = wt[(size_t)pt[2] * T + ct];
  o.w = wt[(size_t)pt[3] * T + ct];
  ((float4*)Wp)[n] = o;
}

// ---------------- K3: sequential Viterbi values (bitwise), argmax deferred ----------------
__device__ __forceinline__ void vstep(int t, int par, int w, int j,
                                      float4& w0, float4& w1, float& ss,
                                      float* vitbuf, float (*part)[8][B],
                                      const float* __restrict__ Wp,
                                      const float* __restrict__ bs,
                                      float* __restrict__ vit) {
  float4 va = *(const float4*)&vitbuf[w * 8];
  float4 vb = *(const float4*)&vitbuf[w * 8 + 4];
  float m =          (va.x + ss) + w0.x;
  m = fmaxf(m, (va.y + ss) + w0.y);
  m = fmaxf(m, (va.z + ss) + w0.z);
  m = fmaxf(m, (va.w + ss) + w0.w);
  m = fmaxf(m, (vb.x + ss) + w1.x);
  m = fmaxf(m, (vb.y + ss) + w1.y);
  m = fmaxf(m, (vb.z + ss) + w1.z);
  m = fmaxf(m, (vb.w + ss) + w1.w);
  part[par][w][j] = m;
  // prefetch step t+2 into the buffer we just consumed
  if (t + 2 <= NSTEP) {
    const float4* q = (const float4*)(Wp + (((size_t)(t + 1) * B + j) * B + (w << 3)));
    w0 = q[0]; w1 = q[1];
    ss = bs[(size_t)(t + 2) * B + j];
  }
  __syncthreads();
  float nv = part[par][0][j];
  nv = fmaxf(nv, part[par][1][j]);
  nv = fmaxf(nv, part[par][2][j]);
  nv = fmaxf(nv, part[par][3][j]);
  nv = fmaxf(nv, part[par][4][j]);
  nv = fmaxf(nv, part[par][5][j]);
  nv = fmaxf(nv, part[par][6][j]);
  nv = fmaxf(nv, part[par][7][j]);
  vitbuf[j] = nv;  // all waves write identical value; own write orders own next read
  if (w == 0) vit[(size_t)t * B + j] = nv;
}

__global__ __launch_bounds__(512) void k_seqvit_pre(const float* __restrict__ bs,
                                                    const float* __restrict__ Wp,
                                                    float* __restrict__ vit) {
  __shared__ alignas(16) float vitbuf[B];
  __shared__ float part[2][8][B];
  int tid = threadIdx.x, w = tid >> 6, j = tid & 63;
  float v0 = bs[j];
  vitbuf[j] = v0;
  if (w == 0) vit[j] = v0;
  float4 wA0, wA1, wB0, wB1;
  float sA, sB;
  {
    const float4* q1 = (const float4*)(Wp + (((size_t)0 * B + j) * B + (w << 3)));
    wA0 = q1[0]; wA1 = q1[1]; sA = bs[(size_t)1 * B + j];
    const float4* q2 = (const float4*)(Wp + (((size_t)1 * B + j) * B + (w << 3)));
    wB0 = q2[0]; wB1 = q2[1]; sB = bs[(size_t)2 * B + j];
  }
  __syncthreads();
  for (int t = 1; t <= NSTEP; t += 2) {
    vstep(t, 1, w, j, wA0, wA1, sA, vitbuf, part, Wp, bs, vit);
    if (t + 1 <= NSTEP)
      vstep(t + 1, 0, w, j, wB0, wB1, sB, vitbuf, part, Wp, bs, vit);
  }
}

__global__ __launch_bounds__(512) void k_seqvit_slow(const float* __restrict__ bs,
                                                     const int* __restrict__ bt,
                                                     const float* __restrict__ wt,
                                                     float* __restrict__ vit) {
  __shared__ float vitbuf[B];
  __shared__ int tagbuf[B];
  __shared__ float part[2][8][B];
  int tid = threadIdx.x, w = tid >> 6, j = tid & 63;
  float v0 = bs[j];
  vitbuf[j] = v0;
  tagbuf[j] = bt[j];
  if (w == 0) vit[j] = v0;
  __syncthreads();
  for (int t = 1; t <= NSTEP; ++t) {
    float ss = bs[(size_t)t * B + j];
    int ct = bt[(size_t)t * B + j];
    float m = -3.0e38f;
#pragma unroll
    for (int e = 0; e < 8; ++e) {
      float vi = vitbuf[(w << 3) + e];
      int   pt = tagbuf[(w << 3) + e];
      float wv = wt[(size_t)pt * T + ct];
      m = fmaxf(m, (vi + ss) + wv);
    }
    int par = t & 1;
    part[par][w][j] = m;
    __syncthreads();
    float nv = part[par][0][j];
#pragma unroll
    for (int ww = 1; ww < 8; ++ww) nv = fmaxf(nv, part[par][ww][j]);
    vitbuf[j] = nv;
    tagbuf[j] = ct;
    if (w == 0) vit[(size_t)t * B + j] = nv;
  }
}

// ---------------- K4: forward logsumexp as chunked linear-domain matrix products ----------------
__global__ __launch_bounds__(256) void k_fwdchunk(const float* __restrict__ bs,
                                                  const int* __restrict__ bt,
                                                  const float* __restrict__ Wp,
                                                  const float* __restrict__ wt,
                                                  float* __restrict__ Gt, int usePre) {
  __shared__ alignas(16) float Pt[2][B][68];  // Pt[buf][j][i] = P[i][j], padded stride 68
  __shared__ float X[B][B];
  __shared__ alignas(16) float Rk[B];
  __shared__ float Qi[B];
  __shared__ float pmx[4][B];
  __shared__ int ptl[B];
  int tid = threadIdx.x, r = tid >> 6, j = tid & 63;
  int c = blockIdx.x;
  int t0 = c * CH + 1;
  int t1 = min(c * CH + CH, NSTEP);
#pragma unroll
  for (int e = 0; e < 16; ++e) {
    int i = 16 * r + e;
    Pt[0][j][i] = (i == j) ? 1.0f : 0.0f;
  }
  if (r == 0) { Rk[j] = 0.0f; Qi[j] = 0.0f; }
  __syncthreads();
  int pb = 0;
  for (int t = t0; t <= t1; ++t) {
    float ev[16];
    if (usePre) {
      const float4* q = (const float4*)(Wp + (((size_t)(t - 1) * B + j) * B + 16 * r));
      float4 q0 = q[0], q1 = q[1], q2 = q[2], q3 = q[3];
      ev[0] = q0.x; ev[1] = q0.y; ev[2] = q0.z; ev[3] = q0.w;
      ev[4] = q1.x; ev[5] = q1.y; ev[6] = q1.z; ev[7] = q1.w;
      ev[8] = q2.x; ev[9] = q2.y; ev[10] = q2.z; ev[11] = q2.w;
      ev[12] = q3.x; ev[13] = q3.y; ev[14] = q3.z; ev[15] = q3.w;
    } else {
      if (tid < B) ptl[tid] = bt[(size_t)(t - 1) * B + tid];
      __syncthreads();
      int ct = bt[(size_t)t * B + j];
#pragma unroll
      for (int e = 0; e < 16; ++e) ev[e] = wt[(size_t)ptl[16 * r + e] * T + ct];
    }
    {
      const float4* rq = (const float4*)&Rk[16 * r];
      float4 r0 = rq[0], r1 = rq[1], r2 = rq[2], r3 = rq[3];
      ev[0] += r0.x; ev[1] += r0.y; ev[2] += r0.z; ev[3] += r0.w;
      ev[4] += r1.x; ev[5] += r1.y; ev[6] += r1.z; ev[7] += r1.w;
      ev[8] += r2.x; ev[9] += r2.y; ev[10] += r2.z; ev[11] += r2.w;
      ev[12] += r3.x; ev[13] += r3.y; ev[14] += r3.z; ev[15] += r3.w;
    }
    float pm = ev[0];
#pragma unroll
    for (int e = 1; e < 16; ++e) pm = fmaxf(pm, ev[e]);
    pmx[r][j] = pm;
    __syncthreads();
    float Mw = fmaxf(fmaxf(pmx[0][j], pmx[1][j]), fmaxf(pmx[2][j], pmx[3][j]));
#pragma unroll
    for (int e = 0; e < 16; ++e)
      X[16 * r + e][j] = exp2f(K2E * (ev[e] - Mw) - 6.0f);
    __syncthreads();
    if (r == 0) Rk[j] = (bs[(size_t)t * B + j] + Mw) + LN64;  // consumed next step, after BAR-B
    float acc[16];
#pragma unroll
    for (int e = 0; e < 16; ++e) acc[e] = 0.0f;
    for (int k = 0; k < B; ++k) {
      float xk = X[k][j];
      const float4* pr = (const float4*)&Pt[pb][k][16 * r];
      float4 p0 = pr[0], p1 = pr[1], p2 = pr[2], p3 = pr[3];
      acc[0] = fmaf(p0.x, xk, acc[0]);   acc[1] = fmaf(p0.y, xk, acc[1]);
      acc[2] = fmaf(p0.z, xk, acc[2]);   acc[3] = fmaf(p0.w, xk, acc[3]);
      acc[4] = fmaf(p1.x, xk, acc[4]);   acc[5] = fmaf(p1.y, xk, acc[5]);
      acc[6] = fmaf(p1.z, xk, acc[6]);   acc[7] = fmaf(p1.w, xk, acc[7]);
      acc[8] = fmaf(p2.x, xk, acc[8]);   acc[9] = fmaf(p2.y, xk, acc[9]);
      acc[10] = fmaf(p2.z, xk, acc[10]); acc[11] = fmaf(p2.w, xk, acc[11]);
      acc[12] = fmaf(p3.x, xk, acc[12]); acc[13] = fmaf(p3.y, xk, acc[13]);
      acc[14] = fmaf(p3.z, xk, acc[14]); acc[15] = fmaf(p3.w, xk, acc[15]);
    }
#pragma unroll
    for (int e = 0; e < 4; ++e) {
      float4 o;
      o.x = acc[4 * e]; o.y = acc[4 * e + 1]; o.z = acc[4 * e + 2]; o.w = acc[4 * e + 3];
      *(float4*)&Pt[1 - pb][j][16 * r + 4 * e] = o;
    }
    pb ^= 1;
    __syncthreads();
    if (((t - t0) & 15) == 15 && t != t1) {
      // renormalize rows of P (columns of Pt): thread acts as (r, i=j)
      int i = j;
      float qm = Pt[pb][16 * r][i];
#pragma unroll
      for (int e = 1; e < 16; ++e) qm = fmaxf(qm, Pt[pb][16 * r + e][i]);
      pmx[r][i] = qm;
      __syncthreads();
      float qv = fmaxf(fmaxf(pmx[0][i], pmx[1][i]), fmaxf(pmx[2][i], pmx[3][i]));
      float inv = 1.0f / qv;
#pragma unroll
      for (int e = 0; e < 16; ++e) Pt[pb][16 * r + e][i] *= inv;
      if (r == 0) Qi[i] += LN2 * log2f(qv);
      __syncthreads();
    }
  }
  float rj = Rk[j];
#pragma unroll
  for (int e = 0; e < 16; ++e) {
    int i = 16 * r + e;
    float p = Pt[pb][j][i];
    float g = (p > 0.0f) ? (Qi[i] + rj + LN2 * log2f(p)) : -3.0e38f;
    Gt[((size_t)c * B + j) * B + i] = g;
  }
}

// ---------------- K5: sequential chunk combine + logZ + output scalar ----------------
__global__ __launch_bounds__(256) void k_combine(const float* __restrict__ bs,
                                                 const float* __restrict__ Gt,
                                                 const float* __restrict__ scal,
                                                 float* __restrict__ out) {
  __shared__ alignas(16) float fbuf[B];
  __shared__ float pmm[2][4][B];
  __shared__ float pss[2][4][B];
  int tid = threadIdx.x, r = tid >> 6, j = tid & 63;
  fbuf[j] = bs[j];
  __syncthreads();
  for (int c = 0; c < NC; ++c) {
    const float4* gq = (const float4*)(Gt + ((size_t)c * B + j) * B + 16 * r);
    float4 g0 = gq[0], g1 = gq[1], g2 = gq[2], g3 = gq[3];
    const float4* fp = (const float4*)&fbuf[16 * r];
    float4 f0 = fp[0], f1 = fp[1], f2 = fp[2], f3 = fp[3];
    float a[16];
    a[0] = f0.x + g0.x; a[1] = f0.y + g0.y; a[2] = f0.z + g0.z; a[3] = f0.w + g0.w;
    a[4] = f1.x + g1.x; a[5] = f1.y + g1.y; a[6] = f1.z + g1.z; a[7] = f1.w + g1.w;
    a[8] = f2.x + g2.x; a[9] = f2.y + g2.y; a[10] = f2.z + g2.z; a[11] = f2.w + g2.w;
    a[12] = f3.x + g3.x; a[13] = f3.y + g3.y; a[14] = f3.z + g3.z; a[15] = f3.w + g3.w;
    float M = a[0];
#pragma unroll
    for (int u = 1; u < 16; ++u) M = fmaxf(M, a[u]);
    int pc = c & 1;
    pmm[pc][r][j] = M;
    __syncthreads();
    M = fmaxf(fmaxf(pmm[pc][0][j], pmm[pc][1][j]), fmaxf(pmm[pc][2][j], pmm[pc][3][j]));
    float ssum = 0.0f;
#pragma unroll
    for (int u = 0; u < 16; ++u) ssum += exp2f(K2E * (a[u] - M));
    pss[pc][r][j] = ssum;
    __syncthreads();
    float tot = pss[pc][0][j] + pss[pc][1][j] + pss[pc][2][j] + pss[pc][3][j];
    fbuf[j] = M + LN2 * log2f(tot);
  }
  __syncthreads();
  if (tid < 64) {
    float f = fbuf[tid];
    float M = f;
#pragma unroll
    for (int off = 32; off >= 1; off >>= 1) M = fmaxf(M, __shfl_xor(M, off));
    float sv = exp2f(K2E * (f - M));
#pragma unroll
    for (int off = 32; off >= 1; off >>= 1) sv += __shfl_xor(sv, off);
    if (tid == 0) out[S] = (M + LN2 * log2f(sv)) - scal[0];
  }
}

// ---------------- K6: parallel backpointer recompute (bitwise-identical candidates) ----------------
__global__ __launch_bounds__(256) void k_bp(const float* __restrict__ bs,
                                            const int* __restrict__ bt,
                                            const float* __restrict__ Wp,
                                            const float* __restrict__ wt,
                                            const float* __restrict__ vit,
                                            int* __restrict__ bp, int usePre) {
  int t = blockIdx.x + 1;
  int tid = threadIdx.x, r = tid >> 6, j = tid & 63;
  __shared__ alignas(16) float vl[B];
  __shared__ int ptl[B];
  __shared__ float pmv[4][B];
  __shared__ int pma[4][B];
  if (tid < B) {
    vl[tid] = vit[(size_t)(t - 1) * B + tid];
    ptl[tid] = usePre ? 0 : bt[(size_t)(t - 1) * B + tid];
  }
  __syncthreads();
  float s = bs[(size_t)t * B + j];
  float m; int a;
  if (usePre) {
    const float4* q = (const float4*)(Wp + (((size_t)(t - 1) * B + j) * B + 16 * r));
    float4 q0 = q[0], q1 = q[1], q2 = q[2], q3 = q[3];
    float wv[16] = {q0.x, q0.y, q0.z, q0.w, q1.x, q1.y, q1.z, q1.w,
                    q2.x, q2.y, q2.z, q2.w, q3.x, q3.y, q3.z, q3.w};
    m = (vl[16 * r] + s) + wv[0];
    a = 16 * r;
#pragma unroll
    for (int e = 1; e < 16; ++e) {
      float cv = (vl[16 * r + e] + s) + wv[e];
      if (cv > m) { m = cv; a = 16 * r + e; }
    }
  } else {
    int ct = bt[(size_t)t * B + j];
    m = -3.0e38f; a = 16 * r;
#pragma unroll
    for (int e = 0; e < 16; ++e) {
      float cv = (vl[16 * r + e] + s) + wt[(size_t)ptl[16 * r + e] * T + ct];
      if (cv > m) { m = cv; a = 16 * r + e; }
    }
  }
  pmv[r][j] = m; pma[r][j] = a;
  __syncthreads();
  if (r == 0) {
#pragma unroll
    for (int ww = 1; ww < 4; ++ww) {
      float om = pmv[ww][j];
      if (om > m) { m = om; a = pma[ww][j]; }
    }
    bp[(size_t)t * B + j] = a;
  }
}

// ---------------- K7a: per-chunk backtrack maps ----------------
__global__ __launch_bounds__(64) void k_chunkback(const int* __restrict__ bp,
                                                  int* __restrict__ map) {
  int c = blockIdx.x, lane = threadIdx.x;
  int t0 = c * CH + 1;
  int t1 = min(c * CH + CH, NSTEP);
  int nst = t1 - t0 + 1;
  __shared__ int bpl[CH][B];
  for (int tt = 0; tt < nst; ++tt) bpl[tt][lane] = bp[(size_t)(t0 + tt) * B + lane];
  __syncthreads();
  int cur = lane;
  for (int tt = nst - 1; tt >= 0; --tt) cur = bpl[tt][cur];
  map[c * B + lane] = cur;
}

// ---------------- K7b: argmax(final vit) + sequential boundary chain ----------------
__global__ __launch_bounds__(256) void k_bound(const float* __restrict__ vit,
                                               const int* __restrict__ map,
                                               int* __restrict__ bnd) {
  __shared__ unsigned char ml[NC * B];
  __shared__ int lastSh;
  int tid = threadIdx.x;
  for (int k = tid; k < NC * B; k += 256) ml[k] = (unsigned char)map[k];
  if (tid < 64) {
    float v = vit[(size_t)NSTEP * B + tid];
    int a = tid;
#pragma unroll
    for (int off = 32; off >= 1; off >>= 1) {
      float ov = __shfl_xor(v, off);
      int   oa = __shfl_xor(a, off);
      if (ov > v || (ov == v && oa < a)) { v = ov; a = oa; }
    }
    if (tid == 0) lastSh = a;
  }
  __syncthreads();
  if (tid == 0) {
    int cur = lastSh;
    bnd[NC] = cur;
    for (int c = NC - 1; c >= 0; --c) {
      cur = (int)ml[c * B + cur];
      bnd[c] = cur;
    }
  }
}

// ---------------- K7c: per-chunk path emit -> predicted tags (as float) ----------------
__global__ __launch_bounds__(64) void k_emit(const int* __restrict__ bp,
                                             const int* __restrict__ bnd,
                                             const int* __restrict__ bt,
                                             float* __restrict__ out) {
  int c = blockIdx.x, lane = threadIdx.x;
  int t0 = c * CH + 1;
  int t1 = min(c * CH + CH, NSTEP);
  int nst = t1 - t0 + 1;
  __shared__ int bpl[CH][B];
  __shared__ int idxl[CH];
  for (int tt = 0; tt < nst; ++tt) bpl[tt][lane] = bp[(size_t)(t0 + tt) * B + lane];
  __syncthreads();
  if (lane == 0) {
    int cur = bnd[c + 1];
    for (int p = t1 - 1; p >= t0 - 1; --p) {
      cur = bpl[p - (t0 - 1)][cur];
      idxl[p - (t0 - 1)] = cur;
    }
  }
  __syncthreads();
  int p = (t0 - 1) + lane;
  if (lane < nst) {
    int idx = idxl[lane];
    out[p] = (float)bt[(size_t)p * B + idx];
  }
  if (c == NC - 1 && lane == 0) {
    int last = bnd[NC];
    out[S - 1] = (float)bt[(size_t)(S - 1) * B + last];
  }
}

// ---------------- K0b: base + crf scalar sums ----------------
__global__ __launch_bounds__(256) void k_basecrf(const float* __restrict__ scores,
                                                 const float* __restrict__ wt,
                                                 const int* __restrict__ tg,
                                                 float* __restrict__ scal) {
  int n = blockIdx.x * 256 + threadIdx.x;
  float v = 0.0f;
  if (n < S) {
    v = scores[(size_t)n * T + tg[n]];
  } else if (n < S + S - 1) {
    int m = n - S;
    v = wt[(size_t)tg[m] * T + tg[m + 1]];
  }
#pragma unroll
  for (int off = 32; off >= 1; off >>= 1) v += __shfl_xor(v, off);
  if ((threadIdx.x & 63) == 0) atomicAdd(scal, v);
}

// ---------------- launch ----------------
extern "C" void kernel_launch(void* const* d_in, const int* in_sizes, int n_in,
                              void* d_out, int out_size, void* d_ws, size_t ws_size,
                              hipStream_t stream) {
  const float* scores  = (const float*)d_in[0];
  const float* weights = (const float*)d_in[1];
  const int*   tags    = (const int*)d_in[2];
  float* out = (float*)d_out;
  char* ws = (char*)d_ws;

  if (ws_size < OFF_W) return;  // cannot run safely

  float* bs   = (float*)(ws + OFF_BS);
  int*   bt   = (int*)(ws + OFF_BT);
  float* vit  = (float*)(ws + OFF_VIT);
  int*   bp   = (int*)(ws + OFF_BP);
  float* Gt   = (float*)(ws + OFF_GT);
  int*   map  = (int*)(ws + OFF_MAP);
  int*   bnd  = (int*)(ws + OFF_BND);
  float* scal = (float*)(ws + OFF_SCAL);
  float* Wp   = (float*)(ws + OFF_W);
  int usePre = (ws_size >= OFF_W + SZ_W) ? 1 : 0;

  hipMemsetAsync(ws + OFF_SCAL, 0, 64, stream);

  k_topk<<<S, 64, 0, stream>>>(scores, bs, bt);
  if (usePre) {
    k_pregather<<<(NSTEP * B * 16) / 256, 256, 0, stream>>>(weights, bt, Wp);
  }
  k_basecrf<<<(2 * S - 1 + 255) / 256, 256, 0, stream>>>(scores, weights, tags, scal);

  if (usePre) {
    k_seqvit_pre<<<1, 512, 0, stream>>>(bs, Wp, vit);
  } else {
    k_seqvit_slow<<<1, 512, 0, stream>>>(bs, bt, weights, vit);
  }

  k_fwdchunk<<<NC, 256, 0, stream>>>(bs, bt, Wp, weights, Gt, usePre);
  k_bp<<<NSTEP, 256, 0, stream>>>(bs, bt, Wp, weights, vit, bp, usePre);
  k_combine<<<1, 256, 0, stream>>>(bs, Gt, scal, out);
  k_chunkback<<<NC, 64, 0, stream>>>(bp, map);
  k_bound<<<1, 256, 0, stream>>>(vit, map, bnd);
  k_emit<<<NC, 64, 0, stream>>>(bp, bnd, bt, out);
}

// Round 2
// 7878.945 us; speedup vs baseline: 3.4530x; 3.4530x over previous
//
#include <hip/hip_runtime.h>
#include <math.h>

#define S 16384
#define T 1024
#define B 64
#define NSTEP (S - 1)   // 16383 transitions
#define CH 64           // chunk length for fwd/backtrack
#define NC 256          // number of chunks
#define PD 8            // prefetch depth (steps) in k_seqvit_seg

#define K2E 1.44269504088896340736f  // log2(e)
#define LN2 0.69314718055994530942f
#define LN64 4.15888308335967186f

// ---------------- workspace layout (bytes) ----------------
static constexpr size_t SZ_SB   = (size_t)S * B * 4;        // 4 MB
static constexpr size_t OFF_BS  = 0;                        // best_scores f32 [S][B]
static constexpr size_t OFF_BT  = OFF_BS + SZ_SB;           // best_tags  i32 [S][B]
static constexpr size_t OFF_VIT = OFF_BT + SZ_SB;           // vit values f32 [S][B]
static constexpr size_t OFF_BP  = OFF_VIT + SZ_SB;          // backptrs   i32 [S][B] (t>=1)
static constexpr size_t OFF_GT  = OFF_BP + SZ_SB;           // chunk G^T  f32 [NC][B][B]
static constexpr size_t SZ_GT   = (size_t)NC * B * B * 4;   // 4 MB
static constexpr size_t OFF_MAP = OFF_GT + SZ_GT;           // chunk maps i32 [NC][B]
static constexpr size_t OFF_BND = OFF_MAP + (size_t)NC * B * 4; // boundary states i32 [NC+1]
static constexpr size_t OFF_SCAL= OFF_BND + 4096;           // scal[0] = base+crf
static constexpr size_t OFF_W   = OFF_SCAL + 4096;          // pre-gathered W ring f32 [seg][B(j)][B(i)]
static constexpr size_t SZ_W    = (size_t)NSTEP * B * B * 4; // ~256 MB if it all fits

// ---------------- K1: per-row top-64 (bitwise matches jax.lax.top_k ordering) ----------------
__global__ __launch_bounds__(64) void k_topk(const float* __restrict__ scores,
                                             float* __restrict__ bs, int* __restrict__ bt) {
  int row = blockIdx.x;
  int lane = threadIdx.x;
  const float* rp = scores + (size_t)row * T;
  float v[16];
#pragma unroll
  for (int k = 0; k < 16; ++k) v[k] = rp[k * 64 + lane];
  for (int b = 0; b < B; ++b) {
    float lv = v[0]; int lk = 0;
#pragma unroll
    for (int k = 1; k < 16; ++k) {
      if (v[k] > lv) { lv = v[k]; lk = k; }
    }
    float bv = lv; int be = lk * 64 + lane;
#pragma unroll
    for (int off = 32; off >= 1; off >>= 1) {
      float ov = __shfl_xor(bv, off);
      int   oe = __shfl_xor(be, off);
      if (ov > bv || (ov == bv && oe < be)) { bv = ov; be = oe; }
    }
    if (lane == 0) {
      bs[(size_t)row * B + b] = bv;
      bt[(size_t)row * B + b] = be;
    }
    int bk = be >> 6, bl = be & 63;
#pragma unroll
    for (int k = 0; k < 16; ++k) {
      if (k == bk && lane == bl) v[k] = -3.0e38f;
    }
  }
}

// ---------------- K2: pre-gather per-step weight tiles (segmented) ----------------
// Wp[rel][j][i] = w[bt[tbase-1+rel][i]][bt[tbase+rel][j]]   for rel in [0, ns)
__global__ __launch_bounds__(256) void k_pregather(const float* __restrict__ wt,
                                                   const int* __restrict__ bt,
                                                   float* __restrict__ Wp,
                                                   int tbase, int ns) {
  size_t n = (size_t)blockIdx.x * 256 + threadIdx.x;  // one float4 (4 i's) per thread
  int i4  = (int)(n & 15);
  int j   = (int)((n >> 4) & 63);
  int rel = (int)(n >> 10);
  if (rel >= ns) return;
  int tm1 = tbase - 1 + rel;
  int ct = bt[(size_t)(tm1 + 1) * B + j];
  const int* pt = bt + (size_t)tm1 * B + i4 * 4;
  float4 o;
  o.x = wt[(size_t)pt[0] * T + ct];
  o.y = wt[(size_t)pt[1] * T + ct];
  o.z = wt[(size_t)pt[2] * T + ct];
  o.w = wt[(size_t)pt[3] * T + ct];
  ((float4*)Wp)[n] = o;
}

// ---------------- K3: sequential Viterbi over one pre-gathered segment ----------------
// Steps t = t0 .. t0+ns-1. Thread (w,l): j = w*8 + l/8, candidates i = (l%8)*8 .. +8.
// One barrier + one LDS round-trip per step; W prefetched PD steps deep in registers.
__global__ __launch_bounds__(512) void k_seqvit_seg(const float* __restrict__ bs,
                                                    const float* __restrict__ Wp,
                                                    float* __restrict__ vit,
                                                    int t0, int ns) {
  __shared__ alignas(16) float vb[2][B];
  int tid = threadIdx.x, w = tid >> 6, l = tid & 63;
  int j = (w << 3) | (l >> 3);
  int i0 = (l & 7) << 3;
  if (tid < B) {
    float v0 = (t0 == 1) ? bs[tid] : vit[(size_t)(t0 - 1) * B + tid];
    vb[0][tid] = v0;
    if (t0 == 1) vit[tid] = v0;
  }
  const float* wrow = Wp + (size_t)j * B + i0;
  float4 wa[PD], wc[PD];
  float ss[PD];
#pragma unroll
  for (int d = 0; d < PD; ++d) {
    if (d < ns) {
      const float4* q = (const float4*)(wrow + (size_t)d * B * B);
      wa[d] = q[0]; wc[d] = q[1];
      ss[d] = bs[(size_t)(t0 + d) * B + j];
    }
  }
  __syncthreads();
  int p = 0;
  for (int k0 = 0; k0 < ns; k0 += PD) {
#pragma unroll
    for (int ph = 0; ph < PD; ++ph) {
      int k = k0 + ph;
      if (k < ns) {
        float4 A = wa[ph], C = wc[ph];
        float s = ss[ph];
        const float4* vr = (const float4*)&vb[p][i0];
        float4 va = vr[0], v2 = vr[1];
        float m0 = fmaxf((va.x + s) + A.x, (va.y + s) + A.y);
        float m1 = fmaxf((va.z + s) + A.z, (va.w + s) + A.w);
        float m2 = fmaxf((v2.x + s) + C.x, (v2.y + s) + C.y);
        float m3 = fmaxf((v2.z + s) + C.z, (v2.w + s) + C.w);
        float m = fmaxf(fmaxf(m0, m1), fmaxf(m2, m3));
        m = fmaxf(m, __shfl_xor(m, 1));
        m = fmaxf(m, __shfl_xor(m, 2));
        m = fmaxf(m, __shfl_xor(m, 4));
        if (k + PD < ns) {
          const float4* q = (const float4*)(wrow + (size_t)(k + PD) * B * B);
          wa[ph] = q[0]; wc[ph] = q[1];
          ss[ph] = bs[(size_t)(t0 + k + PD) * B + j];
        }
        if ((l & 7) == 0) {
          vb[1 - p][j] = m;
          vit[(size_t)(t0 + k) * B + j] = m;
        }
        __syncthreads();
        p ^= 1;
      }
    }
  }
}

// ---------------- K3-fallback: in-loop gather (tiny workspace only) ----------------
__global__ __launch_bounds__(512) void k_seqvit_slow(const float* __restrict__ bs,
                                                     const int* __restrict__ bt,
                                                     const float* __restrict__ wt,
                                                     float* __restrict__ vit) {
  __shared__ float vitbuf[B];
  __shared__ int tagbuf[B];
  __shared__ float part[2][8][B];
  int tid = threadIdx.x, w = tid >> 6, j = tid & 63;
  float v0 = bs[j];
  vitbuf[j] = v0;
  tagbuf[j] = bt[j];
  if (w == 0) vit[j] = v0;
  __syncthreads();
  for (int t = 1; t <= NSTEP; ++t) {
    float ss = bs[(size_t)t * B + j];
    int ct = bt[(size_t)t * B + j];
    float m = -3.0e38f;
#pragma unroll
    for (int e = 0; e < 8; ++e) {
      float vi = vitbuf[(w << 3) + e];
      int   pt = tagbuf[(w << 3) + e];
      float wv = wt[(size_t)pt * T + ct];
      m = fmaxf(m, (vi + ss) + wv);
    }
    int par = t & 1;
    part[par][w][j] = m;
    __syncthreads();
    float nv = part[par][0][j];
#pragma unroll
    for (int ww = 1; ww < 8; ++ww) nv = fmaxf(nv, part[par][ww][j]);
    vitbuf[j] = nv;
    tagbuf[j] = ct;
    if (w == 0) vit[(size_t)t * B + j] = nv;
  }
}

// ---------------- K4: forward logsumexp as chunked linear-domain matrix products ----------------
__global__ __launch_bounds__(256) void k_fwdchunk(const float* __restrict__ bs,
                                                  const int* __restrict__ bt,
                                                  const float* __restrict__ Wp,
                                                  const float* __restrict__ wt,
                                                  float* __restrict__ Gt, int usePre) {
  __shared__ alignas(16) float Pt[2][B][68];  // Pt[buf][j][i] = P[i][j], padded stride 68
  __shared__ float X[B][B];
  __shared__ alignas(16) float Rk[B];
  __shared__ float Qi[B];
  __shared__ float pmx[4][B];
  __shared__ int ptl[B];
  int tid = threadIdx.x, r = tid >> 6, j = tid & 63;
  int c = blockIdx.x;
  int t0 = c * CH + 1;
  int t1 = min(c * CH + CH, NSTEP);
#pragma unroll
  for (int e = 0; e < 16; ++e) {
    int i = 16 * r + e;
    Pt[0][j][i] = (i == j) ? 1.0f : 0.0f;
  }
  if (r == 0) { Rk[j] = 0.0f; Qi[j] = 0.0f; }
  __syncthreads();
  int pb = 0;
  for (int t = t0; t <= t1; ++t) {
    float ev[16];
    if (usePre) {
      const float4* q = (const float4*)(Wp + (((size_t)(t - 1) * B + j) * B + 16 * r));
      float4 q0 = q[0], q1 = q[1], q2 = q[2], q3 = q[3];
      ev[0] = q0.x; ev[1] = q0.y; ev[2] = q0.z; ev[3] = q0.w;
      ev[4] = q1.x; ev[5] = q1.y; ev[6] = q1.z; ev[7] = q1.w;
      ev[8] = q2.x; ev[9] = q2.y; ev[10] = q2.z; ev[11] = q2.w;
      ev[12] = q3.x; ev[13] = q3.y; ev[14] = q3.z; ev[15] = q3.w;
    } else {
      if (tid < B) ptl[tid] = bt[(size_t)(t - 1) * B + tid];
      __syncthreads();
      int ct = bt[(size_t)t * B + j];
#pragma unroll
      for (int e = 0; e < 16; ++e) ev[e] = wt[(size_t)ptl[16 * r + e] * T + ct];
    }
    {
      const float4* rq = (const float4*)&Rk[16 * r];
      float4 r0 = rq[0], r1 = rq[1], r2 = rq[2], r3 = rq[3];
      ev[0] += r0.x; ev[1] += r0.y; ev[2] += r0.z; ev[3] += r0.w;
      ev[4] += r1.x; ev[5] += r1.y; ev[6] += r1.z; ev[7] += r1.w;
      ev[8] += r2.x; ev[9] += r2.y; ev[10] += r2.z; ev[11] += r2.w;
      ev[12] += r3.x; ev[13] += r3.y; ev[14] += r3.z; ev[15] += r3.w;
    }
    float pm = ev[0];
#pragma unroll
    for (int e = 1; e < 16; ++e) pm = fmaxf(pm, ev[e]);
    pmx[r][j] = pm;
    __syncthreads();
    float Mw = fmaxf(fmaxf(pmx[0][j], pmx[1][j]), fmaxf(pmx[2][j], pmx[3][j]));
#pragma unroll
    for (int e = 0; e < 16; ++e)
      X[16 * r + e][j] = exp2f(K2E * (ev[e] - Mw) - 6.0f);
    __syncthreads();
    if (r == 0) Rk[j] = (bs[(size_t)t * B + j] + Mw) + LN64;  // consumed next step
    float acc[16];
#pragma unroll
    for (int e = 0; e < 16; ++e) acc[e] = 0.0f;
    for (int k = 0; k < B; ++k) {
      float xk = X[k][j];
      const float4* pr = (const float4*)&Pt[pb][k][16 * r];
      float4 p0 = pr[0], p1 = pr[1], p2 = pr[2], p3 = pr[3];
      acc[0] = fmaf(p0.x, xk, acc[0]);   acc[1] = fmaf(p0.y, xk, acc[1]);
      acc[2] = fmaf(p0.z, xk, acc[2]);   acc[3] = fmaf(p0.w, xk, acc[3]);
      acc[4] = fmaf(p1.x, xk, acc[4]);   acc[5] = fmaf(p1.y, xk, acc[5]);
      acc[6] = fmaf(p1.z, xk, acc[6]);   acc[7] = fmaf(p1.w, xk, acc[7]);
      acc[8] = fmaf(p2.x, xk, acc[8]);   acc[9] = fmaf(p2.y, xk, acc[9]);
      acc[10] = fmaf(p2.z, xk, acc[10]); acc[11] = fmaf(p2.w, xk, acc[11]);
      acc[12] = fmaf(p3.x, xk, acc[12]); acc[13] = fmaf(p3.y, xk, acc[13]);
      acc[14] = fmaf(p3.z, xk, acc[14]); acc[15] = fmaf(p3.w, xk, acc[15]);
    }
#pragma unroll
    for (int e = 0; e < 4; ++e) {
      float4 o;
      o.x = acc[4 * e]; o.y = acc[4 * e + 1]; o.z = acc[4 * e + 2]; o.w = acc[4 * e + 3];
      *(float4*)&Pt[1 - pb][j][16 * r + 4 * e] = o;
    }
    pb ^= 1;
    __syncthreads();
    if (((t - t0) & 15) == 15 && t != t1) {
      int i = j;
      float qm = Pt[pb][16 * r][i];
#pragma unroll
      for (int e = 1; e < 16; ++e) qm = fmaxf(qm, Pt[pb][16 * r + e][i]);
      pmx[r][i] = qm;
      __syncthreads();
      float qv = fmaxf(fmaxf(pmx[0][i], pmx[1][i]), fmaxf(pmx[2][i], pmx[3][i]));
      float inv = 1.0f / qv;
#pragma unroll
      for (int e = 0; e < 16; ++e) Pt[pb][16 * r + e][i] *= inv;
      if (r == 0) Qi[i] += LN2 * log2f(qv);
      __syncthreads();
    }
  }
  float rj = Rk[j];
#pragma unroll
  for (int e = 0; e < 16; ++e) {
    int i = 16 * r + e;
    float p = Pt[pb][j][i];
    float g = (p > 0.0f) ? (Qi[i] + rj + LN2 * log2f(p)) : -3.0e38f;
    Gt[((size_t)c * B + j) * B + i] = g;
  }
}

// ---------------- K5: sequential chunk combine + logZ + output scalar ----------------
__global__ __launch_bounds__(256) void k_combine(const float* __restrict__ bs,
                                                 const float* __restrict__ Gt,
                                                 const float* __restrict__ scal,
                                                 float* __restrict__ out) {
  __shared__ alignas(16) float fbuf[B];
  __shared__ float pmm[2][4][B];
  __shared__ float pss[2][4][B];
  int tid = threadIdx.x, r = tid >> 6, j = tid & 63;
  fbuf[j] = bs[j];
  __syncthreads();
  for (int c = 0; c < NC; ++c) {
    const float4* gq = (const float4*)(Gt + ((size_t)c * B + j) * B + 16 * r);
    float4 g0 = gq[0], g1 = gq[1], g2 = gq[2], g3 = gq[3];
    const float4* fp = (const float4*)&fbuf[16 * r];
    float4 f0 = fp[0], f1 = fp[1], f2 = fp[2], f3 = fp[3];
    float a[16];
    a[0] = f0.x + g0.x; a[1] = f0.y + g0.y; a[2] = f0.z + g0.z; a[3] = f0.w + g0.w;
    a[4] = f1.x + g1.x; a[5] = f1.y + g1.y; a[6] = f1.z + g1.z; a[7] = f1.w + g1.w;
    a[8] = f2.x + g2.x; a[9] = f2.y + g2.y; a[10] = f2.z + g2.z; a[11] = f2.w + g2.w;
    a[12] = f3.x + g3.x; a[13] = f3.y + g3.y; a[14] = f3.z + g3.z; a[15] = f3.w + g3.w;
    float M = a[0];
#pragma unroll
    for (int u = 1; u < 16; ++u) M = fmaxf(M, a[u]);
    int pc = c & 1;
    pmm[pc][r][j] = M;
    __syncthreads();
    M = fmaxf(fmaxf(pmm[pc][0][j], pmm[pc][1][j]), fmaxf(pmm[pc][2][j], pmm[pc][3][j]));
    float ssum = 0.0f;
#pragma unroll
    for (int u = 0; u < 16; ++u) ssum += exp2f(K2E * (a[u] - M));
    pss[pc][r][j] = ssum;
    __syncthreads();
    float tot = pss[pc][0][j] + pss[pc][1][j] + pss[pc][2][j] + pss[pc][3][j];
    fbuf[j] = M + LN2 * log2f(tot);
  }
  __syncthreads();
  if (tid < 64) {
    float f = fbuf[tid];
    float M = f;
#pragma unroll
    for (int off = 32; off >= 1; off >>= 1) M = fmaxf(M, __shfl_xor(M, off));
    float sv = exp2f(K2E * (f - M));
#pragma unroll
    for (int off = 32; off >= 1; off >>= 1) sv += __shfl_xor(sv, off);
    if (tid == 0) out[S] = (M + LN2 * log2f(sv)) - scal[0];
  }
}

// ---------------- K6: parallel backpointer recompute (bitwise-identical candidates) ----------------
__global__ __launch_bounds__(256) void k_bp(const float* __restrict__ bs,
                                            const int* __restrict__ bt,
                                            const float* __restrict__ Wp,
                                            const float* __restrict__ wt,
                                            const float* __restrict__ vit,
                                            int* __restrict__ bp, int usePre) {
  int t = blockIdx.x + 1;
  int tid = threadIdx.x, r = tid >> 6, j = tid & 63;
  __shared__ alignas(16) float vl[B];
  __shared__ int ptl[B];
  __shared__ float pmv[4][B];
  __shared__ int pma[4][B];
  if (tid < B) {
    vl[tid] = vit[(size_t)(t - 1) * B + tid];
    ptl[tid] = usePre ? 0 : bt[(size_t)(t - 1) * B + tid];
  }
  __syncthreads();
  float s = bs[(size_t)t * B + j];
  float m; int a;
  if (usePre) {
    const float4* q = (const float4*)(Wp + (((size_t)(t - 1) * B + j) * B + 16 * r));
    float4 q0 = q[0], q1 = q[1], q2 = q[2], q3 = q[3];
    float wv[16] = {q0.x, q0.y, q0.z, q0.w, q1.x, q1.y, q1.z, q1.w,
                    q2.x, q2.y, q2.z, q2.w, q3.x, q3.y, q3.z, q3.w};
    m = (vl[16 * r] + s) + wv[0];
    a = 16 * r;
#pragma unroll
    for (int e = 1; e < 16; ++e) {
      float cv = (vl[16 * r + e] + s) + wv[e];
      if (cv > m) { m = cv; a = 16 * r + e; }
    }
  } else {
    int ct = bt[(size_t)t * B + j];
    m = -3.0e38f; a = 16 * r;
#pragma unroll
    for (int e = 0; e < 16; ++e) {
      float cv = (vl[16 * r + e] + s) + wt[(size_t)ptl[16 * r + e] * T + ct];
      if (cv > m) { m = cv; a = 16 * r + e; }
    }
  }
  pmv[r][j] = m; pma[r][j] = a;
  __syncthreads();
  if (r == 0) {
#pragma unroll
    for (int ww = 1; ww < 4; ++ww) {
      float om = pmv[ww][j];
      if (om > m) { m = om; a = pma[ww][j]; }
    }
    bp[(size_t)t * B + j] = a;
  }
}

// ---------------- K7a: per-chunk backtrack maps ----------------
__global__ __launch_bounds__(64) void k_chunkback(const int* __restrict__ bp,
                                                  int* __restrict__ map) {
  int c = blockIdx.x, lane = threadIdx.x;
  int t0 = c * CH + 1;
  int t1 = min(c * CH + CH, NSTEP);
  int nst = t1 - t0 + 1;
  __shared__ int bpl[CH][B];
  for (int tt = 0; tt < nst; ++tt) bpl[tt][lane] = bp[(size_t)(t0 + tt) * B + lane];
  __syncthreads();
  int cur = lane;
  for (int tt = nst - 1; tt >= 0; --tt) cur = bpl[tt][cur];
  map[c * B + lane] = cur;
}

// ---------------- K7b: argmax(final vit) + sequential boundary chain ----------------
__global__ __launch_bounds__(256) void k_bound(const float* __restrict__ vit,
                                               const int* __restrict__ map,
                                               int* __restrict__ bnd) {
  __shared__ unsigned char ml[NC * B];
  __shared__ int lastSh;
  int tid = threadIdx.x;
  for (int k = tid; k < NC * B; k += 256) ml[k] = (unsigned char)map[k];
  if (tid < 64) {
    float v = vit[(size_t)NSTEP * B + tid];
    int a = tid;
#pragma unroll
    for (int off = 32; off >= 1; off >>= 1) {
      float ov = __shfl_xor(v, off);
      int   oa = __shfl_xor(a, off);
      if (ov > v || (ov == v && oa < a)) { v = ov; a = oa; }
    }
    if (tid == 0) lastSh = a;
  }
  __syncthreads();
  if (tid == 0) {
    int cur = lastSh;
    bnd[NC] = cur;
    for (int c = NC - 1; c >= 0; --c) {
      cur = (int)ml[c * B + cur];
      bnd[c] = cur;
    }
  }
}

// ---------------- K7c: per-chunk path emit -> predicted tags (as float) ----------------
__global__ __launch_bounds__(64) void k_emit(const int* __restrict__ bp,
                                             const int* __restrict__ bnd,
                                             const int* __restrict__ bt,
                                             float* __restrict__ out) {
  int c = blockIdx.x, lane = threadIdx.x;
  int t0 = c * CH + 1;
  int t1 = min(c * CH + CH, NSTEP);
  int nst = t1 - t0 + 1;
  __shared__ int bpl[CH][B];
  __shared__ int idxl[CH];
  for (int tt = 0; tt < nst; ++tt) bpl[tt][lane] = bp[(size_t)(t0 + tt) * B + lane];
  __syncthreads();
  if (lane == 0) {
    int cur = bnd[c + 1];
    for (int p = t1 - 1; p >= t0 - 1; --p) {
      cur = bpl[p - (t0 - 1)][cur];
      idxl[p - (t0 - 1)] = cur;
    }
  }
  __syncthreads();
  int p = (t0 - 1) + lane;
  if (lane < nst) {
    int idx = idxl[lane];
    out[p] = (float)bt[(size_t)p * B + idx];
  }
  if (c == NC - 1 && lane == 0) {
    int last = bnd[NC];
    out[S - 1] = (float)bt[(size_t)(S - 1) * B + last];
  }
}

// ---------------- K0b: base + crf scalar sums ----------------
__global__ __launch_bounds__(256) void k_basecrf(const float* __restrict__ scores,
                                                 const float* __restrict__ wt,
                                                 const int* __restrict__ tg,
                                                 float* __restrict__ scal) {
  int n = blockIdx.x * 256 + threadIdx.x;
  float v = 0.0f;
  if (n < S) {
    v = scores[(size_t)n * T + tg[n]];
  } else if (n < S + S - 1) {
    int m = n - S;
    v = wt[(size_t)tg[m] * T + tg[m + 1]];
  }
#pragma unroll
  for (int off = 32; off >= 1; off >>= 1) v += __shfl_xor(v, off);
  if ((threadIdx.x & 63) == 0) atomicAdd(scal, v);
}

// ---------------- launch ----------------
extern "C" void kernel_launch(void* const* d_in, const int* in_sizes, int n_in,
                              void* d_out, int out_size, void* d_ws, size_t ws_size,
                              hipStream_t stream) {
  const float* scores  = (const float*)d_in[0];
  const float* weights = (const float*)d_in[1];
  const int*   tags    = (const int*)d_in[2];
  float* out = (float*)d_out;
  char* ws = (char*)d_ws;

  if (ws_size < OFF_W) return;  // cannot run safely

  float* bs   = (float*)(ws + OFF_BS);
  int*   bt   = (int*)(ws + OFF_BT);
  float* vit  = (float*)(ws + OFF_VIT);
  int*   bp   = (int*)(ws + OFF_BP);
  float* Gt   = (float*)(ws + OFF_GT);
  int*   map  = (int*)(ws + OFF_MAP);
  int*   bnd  = (int*)(ws + OFF_BND);
  float* scal = (float*)(ws + OFF_SCAL);
  float* Wp   = (float*)(ws + OFF_W);

  // segment length (steps) that fits in remaining workspace
  size_t avail = ws_size - OFF_W;
  long seg = (long)(avail / ((size_t)B * B * 4));
  if (seg > NSTEP) seg = NSTEP;
  int useSeg = (seg >= 512) ? 1 : 0;
  int usePre = (seg >= NSTEP) ? 1 : 0;  // full Wp persists -> fwd/bp can reuse it

  hipMemsetAsync(ws + OFF_SCAL, 0, 64, stream);

  k_topk<<<S, 64, 0, stream>>>(scores, bs, bt);
  k_basecrf<<<(2 * S - 1 + 255) / 256, 256, 0, stream>>>(scores, weights, tags, scal);

  if (useSeg) {
    for (int t0 = 1; t0 <= NSTEP; t0 += (int)seg) {
      int ns = (int)((NSTEP - t0 + 1 < seg) ? (NSTEP - t0 + 1) : seg);
      int nblk = (int)(((size_t)ns * 1024 + 255) / 256);
      k_pregather<<<nblk, 256, 0, stream>>>(weights, bt, Wp, t0, ns);
      k_seqvit_seg<<<1, 512, 0, stream>>>(bs, Wp, vit, t0, ns);
    }
  } else {
    k_seqvit_slow<<<1, 512, 0, stream>>>(bs, bt, weights, vit);
  }

  k_fwdchunk<<<NC, 256, 0, stream>>>(bs, bt, Wp, weights, Gt, usePre);
  k_bp<<<NSTEP, 256, 0, stream>>>(bs, bt, Wp, weights, vit, bp, usePre);
  k_combine<<<1, 256, 0, stream>>>(bs, Gt, scal, out);
  k_chunkback<<<NC, 64, 0, stream>>>(bp, map);
  k_bound<<<1, 256, 0, stream>>>(vit, map, bnd);
  k_emit<<<NC, 64, 0, stream>>>(bp, bnd, bt, out);
}